// Round 8
// baseline (117.326 us; speedup 1.0000x reference)
//
#include <hip/hip_runtime.h>
#include <stdint.h>

#define DEV __device__ __forceinline__

using bf16x8 = __attribute__((ext_vector_type(8))) short;
using f32x4  = __attribute__((ext_vector_type(4))) float;
using f32x16 = __attribute__((ext_vector_type(16))) float;

DEV float b2f(uint16_t h){ return __uint_as_float(((uint32_t)h)<<16); }
DEV uint16_t f2b(float f){ uint32_t u=__float_as_uint(f); u += 0x7fffu + ((u>>16)&1u); return (uint16_t)(u>>16); }
// pack two f32 -> (bf16(a) | bf16(b)<<16), truncating round (1 v_perm_b32)
DEV uint32_t pk2(float a, float b){
  return __builtin_amdgcn_perm(__float_as_uint(b), __float_as_uint(a), 0x07060302u);
}

// async global->LDS, 16B per lane; LDS dest must be wave-uniform base + lane*16
#define GLOAD16(gp, lp) __builtin_amdgcn_global_load_lds( \
    (__attribute__((address_space(1))) void*)(gp), \
    (__attribute__((address_space(3))) void*)(lp), 16, 0, 0)

constexpr int S_    = 2048;
constexpr int HID   = 896;
constexpr int NH    = 14;
constexpr int NKV   = 2;
constexpr int HD    = 64;
constexpr int BATCH = 2;
constexpr int MROWS = BATCH * S_;   // 4096
constexpr int NQKV  = 1152;         // 896 + 128 + 128
constexpr int SROWS = 1536;         // rows s in [512,2048) have split partials
constexpr int OPSTR = BATCH * NH * SROWS * 64;   // elements per partial slot
constexpr int MLSTR = BATCH * NH * SROWS;        // float2 per partial slot

// ---------------- elementwise f32 -> bf16 (4/thread) ----------------
__global__ void cvt_x_kernel(const float* __restrict__ in, uint16_t* __restrict__ out) {
  int i = blockIdx.x * 256 + threadIdx.x;
  float4 v = ((const float4*)in)[i];
  union { uint16_t u[4]; uint64_t q; } r;
  r.u[0] = f2b(v.x); r.u[1] = f2b(v.y); r.u[2] = f2b(v.z); r.u[3] = f2b(v.w);
  ((uint64_t*)out)[i] = r.q;
}

// ---- weight pack: W (896 x ncols, f32) -> rows [rowOff, rowOff+ncols) of B^T (x896, bf16)
__global__ void pack_wT_kernel(const float* __restrict__ in, uint16_t* __restrict__ out,
                               int ncols, int rowOff) {
  __shared__ uint16_t tile[32][33];
  int n0 = blockIdx.x * 32, k0 = blockIdx.y * 32;
  int lx = threadIdx.x, ly = threadIdx.y;   // 32 x 8
  #pragma unroll
  for (int i = 0; i < 32; i += 8)
    tile[ly + i][lx] = f2b(in[(size_t)(k0 + ly + i) * ncols + (n0 + lx)]);
  __syncthreads();
  #pragma unroll
  for (int i = 0; i < 32; i += 8)
    out[(size_t)(rowOff + n0 + ly + i) * 896 + (k0 + lx)] = tile[lx][ly + i];
}

// ---------------- concat bias bq|bk|bv -> f32[1152] ----------------
__global__ void pack_bias_kernel(const float* __restrict__ bq, const float* __restrict__ bk,
                                 const float* __restrict__ bv, float* __restrict__ out) {
  int i = blockIdx.x * 256 + threadIdx.x;
  if (i >= NQKV) return;
  out[i] = i < 896 ? bq[i] : (i < 1024 ? bk[i - 896] : bv[i - 1024]);
}

// ---------------- RoPE cos/sin table (S x 32, f32) ----------------
__global__ void rope_table_kernel(const int* __restrict__ pos0,
                                  float* __restrict__ cosT, float* __restrict__ sinT) {
  int idx = blockIdx.x * 256 + threadIdx.x;   // S*32
  int s = idx >> 5, j = idx & 31;
  float inv = exp2f(-(float)j * (19.931568569324174f / 32.0f));  // 1e6^(-j/32)
  float ang = (float)(pos0[0] + s) * inv;
  float sv, cv;
  sincosf(ang, &sv, &cv);
  cosT[idx] = cv; sinT[idx] = sv;
}

// ---------------- V: Vf (B,S,128) -> V^T (B,KV,D,S), LDS tile transpose ----------------
__global__ void packv_kernel(const uint16_t* __restrict__ Vf, uint16_t* __restrict__ Vt) {
  __shared__ uint16_t tile[64][65];
  const int s0 = blockIdx.x * 64;
  const int g  = blockIdx.y;                  // b*NKV + kv
  const int b = g >> 1, kv = g & 1;
  const int lx = threadIdx.x & 63, ly = threadIdx.x >> 6;   // 64 x 4
  #pragma unroll
  for (int i = 0; i < 64; i += 4)
    tile[ly + i][lx] = Vf[(size_t)(b * S_ + s0 + ly + i) * 128 + kv * 64 + lx];
  __syncthreads();
  #pragma unroll
  for (int i = 0; i < 64; i += 4)
    Vt[((size_t)g * HD + ly + i) * S_ + s0 + lx] = tile[lx][ly + i];
}

// ---------------- GEMM: C(MxN) = A(MxK,bf16) * Bt(NxK,bf16)^T + bias ----------------
// Tile 128x64, 4 waves of 32x64 (acc[2][4]). EPI 0: f32 C. EPI 1: fused QKV->RoPE.
template <int EPI>
__global__ __launch_bounds__(256) void gemm_bt_kernel(
    const uint16_t* __restrict__ A, const uint16_t* __restrict__ Bt,
    const float* __restrict__ bias, void* __restrict__ Cv, int N, int K,
    const float* __restrict__ cosT, const float* __restrict__ sinT,
    uint16_t* __restrict__ Qb, uint16_t* __restrict__ Kb, uint16_t* __restrict__ Vf) {
  __shared__ __align__(16) uint16_t As[128 * 64];   // 16 KB
  __shared__ __align__(16) uint16_t Bs[64 * 64];    // 8 KB
  const int tid = threadIdx.x;
  const int l = tid & 63, w = tid >> 6;
  const int m0 = blockIdx.x * 128, n0 = blockIdx.y * 64;
  const int wr = w * 32;                            // 32 rows per wave, all 64 cols

  f32x4 acc[2][4] = {};
  for (int k0 = 0; k0 < K; k0 += 64) {
    #pragma unroll
    for (int i = 0; i < 4; ++i) {
      int cid = i * 256 + tid;                 // 1024 A-chunks
      int row = cid >> 3;
      int sch = (cid & 7) ^ (row & 7);
      GLOAD16(A + (size_t)(m0 + row) * K + (k0 + sch * 8), (char*)As + cid * 16);
    }
    #pragma unroll
    for (int i = 0; i < 2; ++i) {
      int cid = i * 256 + tid;                 // 512 B-chunks
      int row = cid >> 3;
      int sch = (cid & 7) ^ (row & 7);
      GLOAD16(Bt + (size_t)(n0 + row) * K + (k0 + sch * 8), (char*)Bs + cid * 16);
    }
    __syncthreads();
    __builtin_amdgcn_s_setprio(1);
    #pragma unroll
    for (int ks = 0; ks < 2; ++ks) {
      bf16x8 af[2], bfr[4];
      #pragma unroll
      for (int mi = 0; mi < 2; ++mi) {
        int row = wr + mi * 16 + (l & 15);
        int ch = ((l >> 4) + ks * 4) ^ (row & 7);
        af[mi] = *(const bf16x8*)((const char*)As + row * 128 + ch * 16);
      }
      #pragma unroll
      for (int ni = 0; ni < 4; ++ni) {
        int row = ni * 16 + (l & 15);
        int ch = ((l >> 4) + ks * 4) ^ (row & 7);
        bfr[ni] = *(const bf16x8*)((const char*)Bs + row * 128 + ch * 16);
      }
      #pragma unroll
      for (int mi = 0; mi < 2; ++mi)
        #pragma unroll
        for (int ni = 0; ni < 4; ++ni)
          acc[mi][ni] = __builtin_amdgcn_mfma_f32_16x16x32_bf16(af[mi], bfr[ni], acc[mi][ni], 0, 0, 0);
    }
    __builtin_amdgcn_s_setprio(0);
    __syncthreads();
  }

  const int tc = l & 15, g = l >> 4;
  if (EPI == 1) {
    if (n0 < 896) {
      // Q head h = n0>>6: RoPE pairs (ni, ni+2), scale 1/8
      #pragma unroll
      for (int mi = 0; mi < 2; ++mi) {
        #pragma unroll
        for (int jr = 0; jr < 4; ++jr) {
          int row = m0 + wr + mi * 16 + g * 4 + jr;
          int bb = row >> 11, s = row & (S_ - 1);
          const float* cp = cosT + s * 32;
          const float* sp = sinT + s * 32;
          #pragma unroll
          for (int ni = 0; ni < 2; ++ni) {
            int col = n0 + ni * 16 + tc;
            int j = col & 63;   // < 32
            float c = cp[j], sn = sp[j];
            float alo = acc[mi][ni][jr] + bias[col];
            float ahi = acc[mi][ni + 2][jr] + bias[col + 32];
            size_t dst = ((size_t)(bb * NH + (n0 >> 6)) * S_ + s) * HD + j;
            Qb[dst]      = f2b((alo * c - ahi * sn) * 0.125f);
            Qb[dst + 32] = f2b((ahi * c + alo * sn) * 0.125f);
          }
        }
      }
    } else if (n0 < 1024) {
      // K head kvh = (n0-896)>>6: RoPE, no scale
      #pragma unroll
      for (int mi = 0; mi < 2; ++mi) {
        #pragma unroll
        for (int jr = 0; jr < 4; ++jr) {
          int row = m0 + wr + mi * 16 + g * 4 + jr;
          int bb = row >> 11, s = row & (S_ - 1);
          const float* cp = cosT + s * 32;
          const float* sp = sinT + s * 32;
          #pragma unroll
          for (int ni = 0; ni < 2; ++ni) {
            int col = n0 + ni * 16 + tc;
            int j = col & 63;   // < 32
            float c = cp[j], sn = sp[j];
            float alo = acc[mi][ni][jr] + bias[col];
            float ahi = acc[mi][ni + 2][jr] + bias[col + 32];
            size_t dst = ((size_t)(bb * NKV + ((n0 - 896) >> 6)) * S_ + s) * HD + j;
            Kb[dst]      = f2b(alo * c - ahi * sn);
            Kb[dst + 32] = f2b(ahi * c + alo * sn);
          }
        }
      }
    } else {
      // V block: plain bf16, row-major Vf (B*S, 128)
      #pragma unroll
      for (int mi = 0; mi < 2; ++mi)
        #pragma unroll
        for (int ni = 0; ni < 4; ++ni) {
          int col = n0 + ni * 16 + tc;
          #pragma unroll
          for (int jr = 0; jr < 4; ++jr) {
            int row = m0 + wr + mi * 16 + g * 4 + jr;
            Vf[(size_t)row * 128 + (col - 1024)] = f2b(acc[mi][ni][jr] + bias[col]);
          }
        }
    }
  } else {
    #pragma unroll
    for (int mi = 0; mi < 2; ++mi) {
      #pragma unroll
      for (int ni = 0; ni < 4; ++ni) {
        int col = n0 + ni * 16 + tc;
        #pragma unroll
        for (int j = 0; j < 4; ++j) {
          int row = m0 + wr + mi * 16 + g * 4 + j;
          ((float*)Cv)[(size_t)row * N + col] = acc[mi][ni][j];
        }
      }
    }
  }
}

// ---------------- Flash attention v7: 32x32x16 fragments, 32 q-rows/wave ----------------
// Block = 448 threads, wave w = head kv*7+w. Unit u in [0,160): (q32, ck) with
// 32-row q-tiles and kv-chunks of <=8 64-tiles. C-layout (32x32): col=l&31,
// row=(reg&3)+8*(reg>>2)+4*(l>>5). P redistribution = half-swap (shfl_xor 32).
__global__ __launch_bounds__(448) void attn_kernel(
    const uint16_t* __restrict__ Qb, const uint16_t* __restrict__ Kb,
    const uint16_t* __restrict__ Vt, uint16_t* __restrict__ Ob,
    uint16_t* __restrict__ Op, float2* __restrict__ mlp) {
  __shared__ __align__(16) uint16_t Ks[2][64 * 64];   // [kv][d], swizzled
  __shared__ __align__(16) uint16_t Vs[2][64 * 64];   // [d][kv], swizzled
  const int tid = threadIdx.x, l = tid & 63, w = tid >> 6;
  const int u = blockIdx.x;
  const int kv = blockIdx.y & 1, b = blockIdx.y >> 1;
  const int l31 = l & 31, hi = l >> 5;

  // decode (q32, ck): q32 0..15:1 chunk, 16..31:2, 32..47:3, 48..63:4
  int q32, ck;
  if (u < 16)      { q32 = u;                 ck = 0; }
  else if (u < 48) { int i = u - 16; q32 = 16 + (i >> 1); ck = i & 1; }
  else if (u < 96) { int i = u - 48; int q3 = i / 3; q32 = 32 + q3; ck = i - 3 * q3; }
  else             { int i = u - 96; q32 = 48 + (i >> 2); ck = i & 3; }
  const int ntiles = (q32 >> 1) + 1;
  const int nch    = (ntiles + 7) >> 3;
  const int tlo    = 8 * ck;
  const int thi    = (tlo + 8 < ntiles) ? (tlo + 8) : ntiles;
  const int ns     = thi - tlo;
  const bool dodiag = (ck == nch - 1);
  const bool split  = (nch > 1);

  const int h  = kv * 7 + w;
  const int qg = q32 * 32 + l31;

  const uint16_t* Khead = Kb + (size_t)(b * NKV + kv) * S_ * HD;
  const uint16_t* Vhead = Vt + (size_t)(b * NKV + kv) * HD * S_;

  // 64x64 bf16 tile = 512 x 16B chunks; 448 lanes + wave0 redo covers all.
  auto stage = [&](int t, int bi) {
    const int t0 = t * 64;
    #pragma unroll
    for (int i = 0; i < 2; ++i) {
      if (i == 0 || tid < 64) {                 // wave-uniform predicate
        int cid = i * 448 + tid;                // 0..511
        int row = cid >> 3, sch = (cid & 7) ^ (row & 7);
        GLOAD16(Khead + (size_t)(t0 + row) * HD + sch * 8, (char*)Ks[bi] + cid * 16);
        GLOAD16(Vhead + (size_t)row * S_ + t0 + sch * 8,   (char*)Vs[bi] + cid * 16);
      }
    }
  };

  // Q fragments (pre-scaled 1/8): lane owns q-row qg; d = 16*ki + 8*hi + j
  const uint16_t* qptr = Qb + ((size_t)(b * NH + h) * S_ + qg) * HD + hi * 8;
  bf16x8 qf[4];
  #pragma unroll
  for (int ki = 0; ki < 4; ++ki) qf[ki] = *(const bf16x8*)(qptr + 16 * ki);

  f32x16 oacc[2] = {};
  float mrow = -1e30f, lrow = 0.f;   // lane-partial over its 32 kv slots

  stage(tlo, 0);

  #pragma unroll 1
  for (int i = 0; i < ns; ++i) {
    const int t = tlo + i;
    asm volatile("s_waitcnt vmcnt(0)" ::: "memory");
    __builtin_amdgcn_s_barrier();
    if (i + 1 < ns) stage(t + 1, (i + 1) & 1);

    const uint16_t* Kc = Ks[i & 1];
    const uint16_t* Vc = Vs[i & 1];
    const int t0 = t * 64;

    // S^T = K * Q^T : sacc[c] = 32x32 tile, row = kv-in-tile, col = q
    f32x16 sacc[2] = {};
    __builtin_amdgcn_s_setprio(1);
    #pragma unroll
    for (int c = 0; c < 2; ++c) {
      int row = c * 32 + l31;
      #pragma unroll
      for (int ki = 0; ki < 4; ++ki) {
        int ch = (2 * ki + hi) ^ (row & 7);
        bf16x8 kf = *(const bf16x8*)((const char*)Kc + row * 128 + ch * 16);
        sacc[c] = __builtin_amdgcn_mfma_f32_32x32x16_bf16(kf, qf[ki], sacc[c], 0, 0, 0);
      }
    }
    __builtin_amdgcn_s_setprio(0);

    // causal mask on diagonal tile only: kv = t0 + 32c + (reg&3) + 8(reg>>2) + 4hi
    if (dodiag && t == ntiles - 1) {
      #pragma unroll
      for (int c = 0; c < 2; ++c)
        #pragma unroll
        for (int reg = 0; reg < 16; ++reg) {
          int kvp = t0 + c * 32 + (reg & 3) + 8 * (reg >> 2) + 4 * hi;
          if (kvp > qg) sacc[c][reg] = -1e30f;
        }
    }

    // T13 defer-max: cross-lane (half-swap) reduce only on significant growth
    float pmax = sacc[0][0];
    #pragma unroll
    for (int c = 0; c < 2; ++c)
      #pragma unroll
      for (int reg = 0; reg < 16; ++reg) pmax = fmaxf(pmax, sacc[c][reg]);
    if (__any(pmax > mrow + 8.f)) {
      float mt = fmaxf(pmax, __shfl_xor(pmax, 32));
      float mn = fmaxf(mrow, mt);
      float corr = __expf(mrow - mn);
      mrow = mn;
      lrow *= corr;
      #pragma unroll
      for (int dt = 0; dt < 2; ++dt)
        #pragma unroll
        for (int reg = 0; reg < 16; ++reg) oacc[dt][reg] *= corr;
    }
    float rs = 0.f;
    #pragma unroll
    for (int c = 0; c < 2; ++c)
      #pragma unroll
      for (int reg = 0; reg < 16; ++reg) {
        float e = __expf(sacc[c][reg] - mrow);
        sacc[c][reg] = e; rs += e;
      }
    lrow += rs;

    // PV: O^T += V^T * P^T, P B-frag built per (c, k2) via half-swap
    __builtin_amdgcn_s_setprio(1);
    #pragma unroll
    for (int c = 0; c < 2; ++c) {
      uint32_t pw[4][2];
      #pragma unroll
      for (int m = 0; m < 4; ++m) {
        pw[m][0] = pk2(sacc[c][4 * m + 0], sacc[c][4 * m + 1]);
        pw[m][1] = pk2(sacc[c][4 * m + 2], sacc[c][4 * m + 3]);
      }
      #pragma unroll
      for (int k2 = 0; k2 < 2; ++k2) {
        uint32_t a0 = pw[2 * k2][0],     a1 = pw[2 * k2][1];
        uint32_t b0 = pw[2 * k2 + 1][0], b1 = pw[2 * k2 + 1][1];
        uint32_t ax0 = __shfl_xor((int)a0, 32), ax1 = __shfl_xor((int)a1, 32);
        uint32_t bx0 = __shfl_xor((int)b0, 32), bx1 = __shfl_xor((int)b1, 32);
        union { uint32_t u[4]; bf16x8 v; } pb;
        pb.u[0] = hi ? bx0 : a0;   // kv = 16ki + 8hi_t + j ; j<4 from half 0
        pb.u[1] = hi ? bx1 : a1;
        pb.u[2] = hi ? b0 : ax0;   // j>=4 from half 1
        pb.u[3] = hi ? b1 : ax1;
        const int ki = 2 * c + k2;
        #pragma unroll
        for (int dt = 0; dt < 2; ++dt) {
          int row = dt * 32 + l31;
          int ch = (2 * ki + hi) ^ (row & 7);
          bf16x8 vf = *(const bf16x8*)((const char*)Vc + row * 128 + ch * 16);
          oacc[dt] = __builtin_amdgcn_mfma_f32_32x32x16_bf16(vf, pb.v, oacc[dt], 0, 0, 0);
        }
      }
    }
    __builtin_amdgcn_s_setprio(0);
  }

  // row total across the two halves
  float ltot = lrow + __shfl_xor(lrow, 32);

  if (!split) {
    float inv = 1.0f / ltot;
    size_t obase = (size_t)(b * S_ + qg) * HID + h * HD;
    #pragma unroll
    for (int dt = 0; dt < 2; ++dt)
      #pragma unroll
      for (int m = 0; m < 4; ++m) {
        union { uint16_t u[4]; uint64_t q; } o;
        #pragma unroll
        for (int r = 0; r < 4; ++r) o.u[r] = f2b(oacc[dt][4 * m + r] * inv);
        *(uint64_t*)(Ob + obase + dt * 32 + m * 8 + hi * 4) = o.q;
      }
  } else {
    size_t rowid = (size_t)(b * NH + h) * SROWS + (qg - 512);
    uint16_t* Opc = Op + (size_t)ck * OPSTR + rowid * 64;
    #pragma unroll
    for (int dt = 0; dt < 2; ++dt)
      #pragma unroll
      for (int m = 0; m < 4; ++m) {
        union { uint16_t u[4]; uint64_t q; } o;
        #pragma unroll
        for (int r = 0; r < 4; ++r) o.u[r] = f2b(oacc[dt][4 * m + r]);
        *(uint64_t*)(Opc + dt * 32 + m * 8 + hi * 4) = o.q;
      }
    if (hi == 0) mlp[(size_t)ck * MLSTR + rowid] = make_float2(mrow, ltot);
  }
}

// ---------------- combine up to 4 partials for rows s >= 512 ----------------
__global__ void combine_kernel(const uint16_t* __restrict__ Op, const float2* __restrict__ mlp,
                               uint16_t* __restrict__ Ob) {
  int idx = blockIdx.x * 256 + threadIdx.x;   // B*NH*SROWS*16
  int r = idx >> 4;                           // (b*NH+h)*SROWS + (s-512)
  int d0 = (idx & 15) * 4;
  int bh = r / SROWS;
  int sr = r - bh * SROWS;
  int s = 512 + sr;
  int nch = (s >> 9) + 1;                     // 2..4
  float M = -1e30f;
  #pragma unroll 4
  for (int c = 0; c < 4; ++c)
    if (c < nch) M = fmaxf(M, mlp[(size_t)c * MLSTR + r].x);
  float den = 0.f, acc[4] = {0.f, 0.f, 0.f, 0.f};
  #pragma unroll 4
  for (int c = 0; c < 4; ++c) {
    if (c >= nch) continue;
    float2 ml = mlp[(size_t)c * MLSTR + r];
    float wg = __expf(ml.x - M);
    den += ml.y * wg;
    union { uint16_t u[4]; uint64_t q; } o;
    o.q = *(const uint64_t*)(Op + (size_t)c * OPSTR + (size_t)r * 64 + d0);
    #pragma unroll
    for (int j = 0; j < 4; ++j) acc[j] += b2f(o.u[j]) * wg;
  }
  float inv = 1.0f / den;
  union { uint16_t u[4]; uint64_t q; } oo;
  #pragma unroll
  for (int j = 0; j < 4; ++j) oo.u[j] = f2b(acc[j] * inv);
  int bb = bh / NH, hh = bh - bb * NH;
  *(uint64_t*)(Ob + (size_t)(bb * S_ + s) * HID + hh * HD + d0) = oo.q;
}

// ---------------- launch ----------------
extern "C" void kernel_launch(void* const* d_in, const int* in_sizes, int n_in,
                              void* d_out, int out_size, void* d_ws, size_t ws_size,
                              hipStream_t stream) {
  (void)in_sizes; (void)n_in; (void)out_size; (void)ws_size;
  const float* X  = (const float*)d_in[0];
  // d_in[1] = attention_mask: pure causal tril, applied analytically in attn_kernel
  const float* Wq = (const float*)d_in[2];
  const float* bq = (const float*)d_in[3];
  const float* Wk = (const float*)d_in[4];
  const float* bk = (const float*)d_in[5];
  const float* Wv = (const float*)d_in[6];
  const float* bv = (const float*)d_in[7];
  const float* Wo = (const float*)d_in[8];
  const int* pos  = (const int*)d_in[9];

  char* p = (char*)d_ws;
  auto carve = [&](size_t n) -> char* { char* r = p; p += (n + 255) & ~(size_t)255; return r; };

  uint16_t* Xb    = (uint16_t*)carve((size_t)MROWS * HID * 2);
  uint16_t* WqkvT = (uint16_t*)carve((size_t)NQKV * 896 * 2);
  uint16_t* WoT   = (uint16_t*)carve((size_t)896 * 896 * 2);
  float*    bqkv  = (float*)carve((size_t)NQKV * 4);
  float*    cosT  = (float*)carve((size_t)S_ * 32 * 4);
  float*    sinT  = (float*)carve((size_t)S_ * 32 * 4);
  uint16_t* Qb    = (uint16_t*)carve((size_t)MROWS * HID * 2);
  uint16_t* Kb    = (uint16_t*)carve((size_t)MROWS * 128 * 2);
  uint16_t* Vf    = (uint16_t*)carve((size_t)MROWS * 128 * 2);
  uint16_t* Vt    = (uint16_t*)carve((size_t)MROWS * 128 * 2);
  uint16_t* Op    = (uint16_t*)carve((size_t)OPSTR * 4 * 2);
  float2*   mlp   = (float2*)carve((size_t)MLSTR * 4 * 8);
  uint16_t* Ob    = Xb;   // Xb dead after QKV gemm; attn/combine write Ob afterwards

  cvt_x_kernel<<<dim3((MROWS * HID / 4) / 256), 256, 0, stream>>>(X, Xb);
  pack_wT_kernel<<<dim3(28, 28), dim3(32, 8), 0, stream>>>(Wq, WqkvT, 896, 0);
  pack_wT_kernel<<<dim3(4, 28),  dim3(32, 8), 0, stream>>>(Wk, WqkvT, 128, 896);
  pack_wT_kernel<<<dim3(4, 28),  dim3(32, 8), 0, stream>>>(Wv, WqkvT, 128, 1024);
  pack_wT_kernel<<<dim3(28, 28), dim3(32, 8), 0, stream>>>(Wo, WoT, 896, 0);
  pack_bias_kernel<<<dim3(5), 256, 0, stream>>>(bq, bk, bv, bqkv);
  rope_table_kernel<<<dim3(S_ * 32 / 256), 256, 0, stream>>>(pos, cosT, sinT);

  gemm_bt_kernel<1><<<dim3(MROWS / 128, NQKV / 64), 256, 0, stream>>>(
      Xb, WqkvT, bqkv, nullptr, NQKV, 896, cosT, sinT, Qb, Kb, Vf);

  packv_kernel<<<dim3(S_ / 64, BATCH * NKV), 256, 0, stream>>>(Vf, Vt);

  attn_kernel<<<dim3(160, NKV * BATCH), 448, 0, stream>>>(Qb, Kb, Vt, Ob, Op, mlp);
  combine_kernel<<<dim3(BATCH * NH * SROWS * 16 / 256), 256, 0, stream>>>(Op, mlp, Ob);

  gemm_bt_kernel<0><<<dim3(MROWS / 128, 896 / 64), 256, 0, stream>>>(
      Ob, WoT, nullptr, d_out, 896, 896, nullptr, nullptr, nullptr, nullptr, nullptr);
}